// Round 1
// baseline (841.792 us; speedup 1.0000x reference)
//
#include <hip/hip_runtime.h>
#include <hip/hip_bf16.h>

// Problem constants
#define EMBED    256
#define HIDDEN   512
#define VOCAB    10000
#define FEAT_DIM 1024
#define BATCH    128
#define NREGS    49
#define TSTEPS   32      // CAPLEN-1

typedef unsigned short u16;
using f32x4 = __attribute__((ext_vector_type(4))) float;
using s16x8 = __attribute__((ext_vector_type(8))) short;

__device__ __forceinline__ u16 f2bf(float f) {
  __hip_bfloat16 h = __float2bfloat16(f);
  return *reinterpret_cast<u16*>(&h);
}
__device__ __forceinline__ float sigmoidf_(float x) {
  return 1.0f / (1.0f + expf(-x));
}

// ---------------------------------------------------------------------------
// Kernel 1: feats_emb[b][e] = (mean_r features[b][r][:]) . W_ft[e][:] + b_ft[e]
// grid 128 blocks (one per batch row), 256 threads
// ---------------------------------------------------------------------------
__global__ __launch_bounds__(256)
void k_feats(const float* __restrict__ features, const float* __restrict__ W_ft,
             const float* __restrict__ b_ft, float* __restrict__ feats_emb) {
  __shared__ float mean[FEAT_DIM];
  int b = blockIdx.x, tid = threadIdx.x;
  const float* fb = features + (size_t)b * NREGS * FEAT_DIM;
  for (int d = tid; d < FEAT_DIM; d += 256) {
    float s = 0.f;
    for (int r = 0; r < NREGS; ++r) s += fb[r * FEAT_DIM + d];
    mean[d] = s * (1.0f / 49.0f);
  }
  __syncthreads();
  // thread tid = output embed index e
  const float* w = W_ft + (size_t)tid * FEAT_DIM;
  float acc = b_ft[tid];
#pragma unroll 4
  for (int d = 0; d < FEAT_DIM; d += 4) {
    float4 m4 = *(const float4*)&mean[d];
    float4 w4 = *(const float4*)&w[d];
    acc += m4.x * w4.x + m4.y * w4.y + m4.z * w4.z + m4.w * w4.w;
  }
  feats_emb[b * EMBED + tid] = acc;
}

// ---------------------------------------------------------------------------
// Kernel 2: weight prep — WcatT/UcatT (transposed, bf16), bcat, Wfc bf16
// grid-stride over 10000*512 elements
// ---------------------------------------------------------------------------
struct GatePtrs {
  const float* W[4];
  const float* U[4];
  const float* b[4];
};

__global__ __launch_bounds__(256)
void k_prep(GatePtrs p, const float* __restrict__ W_fc,
            u16* __restrict__ WcatT, u16* __restrict__ UcatT,
            float* __restrict__ bcat, u16* __restrict__ Wfc_bf) {
  int idx = blockIdx.x * 256 + threadIdx.x;
  if (idx < 4 * HIDDEN * 512) {           // 2048*512
    int j = idx >> 9, k = idx & 511;      // j: T-row (gate-major col), k: K
    int g = j >> 9, jj = j & 511;
    WcatT[idx] = f2bf(p.W[g][k * HIDDEN + jj]);
    UcatT[idx] = f2bf(p.U[g][k * HIDDEN + jj]);
  }
  if (idx < 4 * HIDDEN) bcat[idx] = p.b[idx >> 9][idx & 511];
  if (idx < VOCAB * HIDDEN) Wfc_bf[idx] = f2bf(W_fc[idx]);
}

// ---------------------------------------------------------------------------
// Kernel 3: build X (bf16): row r = t*128+b, cols [emb[cap[b][t]] | feats_emb[b]]
// ---------------------------------------------------------------------------
__global__ __launch_bounds__(256)
void k_build_x(const float* __restrict__ emb, const int* __restrict__ captions,
               const float* __restrict__ feats_emb, u16* __restrict__ X) {
  int idx = blockIdx.x * 256 + threadIdx.x;   // 4096*512 total, exact grid
  int r = idx >> 9, col = idx & 511;
  int t = r >> 7, b = r & 127;
  float v;
  if (col < EMBED) {
    int tok = captions[b * 33 + t];
    v = emb[(size_t)tok * EMBED + col];
  } else {
    v = feats_emb[b * EMBED + (col - EMBED)];
  }
  X[idx] = f2bf(v);
}

// ---------------------------------------------------------------------------
// Kernel 4: bf16 GEMM, C[M][N] = A[M][K] @ Bt[N][K]^T + bias[N]
// 128x128 tile, BK=32, 4 waves, each wave 64x64 (4x4 frags of 16x16x32 MFMA).
// out_mode 0: row-major MxN. out_mode 1: final-proj remap (m=t*128+b -> [b][t][v])
// ---------------------------------------------------------------------------
#define GSTR 40   // LDS row stride in bf16 elements (80B, 16B-aligned, padded)

__global__ __launch_bounds__(256)
void k_gemm_bt(const u16* __restrict__ A, const u16* __restrict__ Bt,
               const float* __restrict__ bias, float* __restrict__ C,
               int M, int N, int K, int out_mode) {
  __shared__ u16 Al[128 * GSTR];
  __shared__ u16 Bl[128 * GSTR];
  int tid = threadIdx.x;
  int lane = tid & 63;
  int w = tid >> 6;
  int wr = w & 1, wc = w >> 1;
  int m0 = blockIdx.y * 128;
  int n0 = blockIdx.x * 128;

  f32x4 acc[4][4];
#pragma unroll
  for (int i = 0; i < 4; ++i)
#pragma unroll
    for (int j = 0; j < 4; ++j) acc[i][j] = (f32x4){0.f, 0.f, 0.f, 0.f};

  // staging: 512 slots of 16B (128 rows x 4 k-chunks); 2 slots per thread
  int s0 = tid, s1 = tid + 256;
  int ar0 = s0 >> 2, ak0 = (s0 & 3) * 8;
  int ar1 = s1 >> 2, ak1 = (s1 & 3) * 8;

  for (int k0 = 0; k0 < K; k0 += 32) {
    uint4 a0 = *(const uint4*)(A + (size_t)(m0 + ar0) * K + k0 + ak0);
    uint4 a1 = *(const uint4*)(A + (size_t)(m0 + ar1) * K + k0 + ak1);
    uint4 b0, b1;
    int bn0 = n0 + ar0, bn1 = n0 + ar1;
    if (bn0 < N) b0 = *(const uint4*)(Bt + (size_t)bn0 * K + k0 + ak0);
    else { b0.x = b0.y = b0.z = b0.w = 0u; }
    if (bn1 < N) b1 = *(const uint4*)(Bt + (size_t)bn1 * K + k0 + ak1);
    else { b1.x = b1.y = b1.z = b1.w = 0u; }

    __syncthreads();   // all waves done reading LDS from previous iter
    *(uint4*)(Al + ar0 * GSTR + ak0) = a0;
    *(uint4*)(Al + ar1 * GSTR + ak1) = a1;
    *(uint4*)(Bl + ar0 * GSTR + ak0) = b0;
    *(uint4*)(Bl + ar1 * GSTR + ak1) = b1;
    __syncthreads();

    // fragments: lane holds row/col = (lane&15), k = 8*(lane>>4)+e
    const u16* ab = Al + (wr * 64 + (lane & 15)) * GSTR + (lane >> 4) * 8;
    const u16* bb = Bl + (wc * 64 + (lane & 15)) * GSTR + (lane >> 4) * 8;
    s16x8 af[4], bf_[4];
#pragma unroll
    for (int mi = 0; mi < 4; ++mi) af[mi] = *(const s16x8*)(ab + mi * 16 * GSTR);
#pragma unroll
    for (int ni = 0; ni < 4; ++ni) bf_[ni] = *(const s16x8*)(bb + ni * 16 * GSTR);
#pragma unroll
    for (int mi = 0; mi < 4; ++mi)
#pragma unroll
      for (int ni = 0; ni < 4; ++ni)
        acc[mi][ni] = __builtin_amdgcn_mfma_f32_16x16x32_bf16(af[mi], bf_[ni], acc[mi][ni], 0, 0, 0);
  }

  // epilogue: C/D frag layout col = lane&15, row = (lane>>4)*4 + reg
  int rbase = (lane >> 4) * 4;
  int colf = lane & 15;
#pragma unroll
  for (int mi = 0; mi < 4; ++mi) {
    int mbase = m0 + wr * 64 + mi * 16 + rbase;
#pragma unroll
    for (int ni = 0; ni < 4; ++ni) {
      int n = n0 + wc * 64 + ni * 16 + colf;
      if (n < N) {
        float bv = bias[n];
#pragma unroll
        for (int reg = 0; reg < 4; ++reg) {
          int mm = mbase + reg;
          float v = acc[mi][ni][reg] + bv;
          if (out_mode == 0) {
            C[(size_t)mm * N + n] = v;
          } else {
            // mm = t*128 + b  ->  out[b][t][n]
            C[(size_t)(mm & 127) * (TSTEPS * VOCAB) + (size_t)(mm >> 7) * VOCAB + n] = v;
          }
        }
      }
    }
  }
}

// ---------------------------------------------------------------------------
// Kernel 5: one LSTM step.  gates = gates_pre[t] + h @ UcatT^T ; cell in f32.
// Block covers all 128 batch rows x 32 j-columns x 4 gates. Grid = 16.
// Wave w: wr=w&1 -> rows 64*wr..+63 ; wj=w>>1 -> j-slice 16*wj..+15.
// acc[mi][gi]: mi = 16-row frag, gi = gate  => each thread holds i,f,g,o
// for its (b,j) in-register; cell epilogue needs no cross-wave exchange.
// ---------------------------------------------------------------------------
__global__ __launch_bounds__(256)
void k_lstm_step(const u16* __restrict__ h_in, const u16* __restrict__ UcatT,
                 const float* __restrict__ gp,   // gates_pre + t*128*2048
                 float* __restrict__ cbuf,
                 u16* __restrict__ h_out, u16* __restrict__ hs_t) {
  __shared__ u16 Al[128 * GSTR];
  __shared__ u16 Bl[128 * GSTR];
  int tid = threadIdx.x;
  int lane = tid & 63;
  int w = tid >> 6;
  int wr = w & 1, wj = w >> 1;
  int j0 = blockIdx.x * 32;

  f32x4 acc[4][4];   // [mi][gate]
#pragma unroll
  for (int i = 0; i < 4; ++i)
#pragma unroll
    for (int j = 0; j < 4; ++j) acc[i][j] = (f32x4){0.f, 0.f, 0.f, 0.f};

  int s0 = tid, s1 = tid + 256;
  int ar0 = s0 >> 2, ak0 = (s0 & 3) * 8;
  int ar1 = s1 >> 2, ak1 = (s1 & 3) * 8;
  // B tile rows c=0..127  <->  UcatT row 512*(c>>5) + j0 + (c&31)
  int br0 = ((ar0 >> 5) << 9) + j0 + (ar0 & 31);
  int br1 = ((ar1 >> 5) << 9) + j0 + (ar1 & 31);

  for (int k0 = 0; k0 < HIDDEN; k0 += 32) {
    uint4 a0 = *(const uint4*)(h_in + (size_t)ar0 * HIDDEN + k0 + ak0);
    uint4 a1 = *(const uint4*)(h_in + (size_t)ar1 * HIDDEN + k0 + ak1);
    uint4 b0 = *(const uint4*)(UcatT + (size_t)br0 * HIDDEN + k0 + ak0);
    uint4 b1 = *(const uint4*)(UcatT + (size_t)br1 * HIDDEN + k0 + ak1);
    __syncthreads();
    *(uint4*)(Al + ar0 * GSTR + ak0) = a0;
    *(uint4*)(Al + ar1 * GSTR + ak1) = a1;
    *(uint4*)(Bl + ar0 * GSTR + ak0) = b0;
    *(uint4*)(Bl + ar1 * GSTR + ak1) = b1;
    __syncthreads();

    const u16* ab = Al + (wr * 64 + (lane & 15)) * GSTR + (lane >> 4) * 8;
    s16x8 af[4], bf_[4];
#pragma unroll
    for (int mi = 0; mi < 4; ++mi) af[mi] = *(const s16x8*)(ab + mi * 16 * GSTR);
#pragma unroll
    for (int gi = 0; gi < 4; ++gi) {
      const u16* bb = Bl + (gi * 32 + wj * 16 + (lane & 15)) * GSTR + (lane >> 4) * 8;
      bf_[gi] = *(const s16x8*)bb;
    }
#pragma unroll
    for (int mi = 0; mi < 4; ++mi)
#pragma unroll
      for (int gi = 0; gi < 4; ++gi)
        acc[mi][gi] = __builtin_amdgcn_mfma_f32_16x16x32_bf16(af[mi], bf_[gi], acc[mi][gi], 0, 0, 0);
  }

  int jj = j0 + wj * 16 + (lane & 15);
  int rbase = (lane >> 4) * 4;
#pragma unroll
  for (int mi = 0; mi < 4; ++mi) {
#pragma unroll
    for (int reg = 0; reg < 4; ++reg) {
      int b = wr * 64 + mi * 16 + rbase + reg;
      const float* g = gp + (size_t)b * (4 * HIDDEN);
      float pi = acc[mi][0][reg] + g[jj];
      float pf = acc[mi][1][reg] + g[HIDDEN + jj];
      float pg = acc[mi][2][reg] + g[2 * HIDDEN + jj];
      float po = acc[mi][3][reg] + g[3 * HIDDEN + jj];
      float iv = sigmoidf_(pi);
      float fv = sigmoidf_(pf);
      float gv = tanhf(pg);
      float ov = sigmoidf_(po);
      size_t ci = (size_t)b * HIDDEN + jj;
      float cn = fv * cbuf[ci] + iv * gv;
      float hn = ov * tanhf(cn);
      cbuf[ci] = cn;
      u16 hb = f2bf(hn);
      h_out[ci] = hb;
      hs_t[ci] = hb;
    }
  }
}

// ---------------------------------------------------------------------------
extern "C" void kernel_launch(void* const* d_in, const int* in_sizes, int n_in,
                              void* d_out, int out_size, void* d_ws, size_t ws_size,
                              hipStream_t stream) {
  const float* features = (const float*)d_in[0];
  const int*   captions = (const int*)d_in[1];
  const float* emb      = (const float*)d_in[2];
  const float* W_ft     = (const float*)d_in[3];
  const float* b_ft     = (const float*)d_in[4];
  GatePtrs p;
  p.W[0] = (const float*)d_in[5];  p.U[0] = (const float*)d_in[6];  p.b[0] = (const float*)d_in[7];
  p.W[1] = (const float*)d_in[8];  p.U[1] = (const float*)d_in[9];  p.b[1] = (const float*)d_in[10];
  p.W[2] = (const float*)d_in[11]; p.U[2] = (const float*)d_in[12]; p.b[2] = (const float*)d_in[13];
  p.W[3] = (const float*)d_in[14]; p.U[3] = (const float*)d_in[15]; p.b[3] = (const float*)d_in[16];
  const float* W_fc = (const float*)d_in[17];
  const float* b_fc = (const float*)d_in[18];
  float* out = (float*)d_out;

  // workspace carve-up (bytes)
  char* ws = (char*)d_ws;
  float* feats_emb = (float*)(ws + 0);            // 128*256*4      = 131072
  u16*   X         = (u16*)(ws + 131072);         // 4096*512*2     = 4194304
  u16*   WcatT     = (u16*)(ws + 4325376);        // 2048*512*2     = 2097152
  u16*   UcatT     = (u16*)(ws + 6422528);        // 2048*512*2     = 2097152
  float* bcat      = (float*)(ws + 8519680);      // 2048*4         = 8192
  u16*   Wfc_bf    = (u16*)(ws + 8527872);        // 10000*512*2    = 10240000
  float* gates_pre = (float*)(ws + 18767872);     // 4096*2048*4    = 33554432
  float* cbuf      = (float*)(ws + 52322304);     // 128*512*4      = 262144
  u16*   h0        = (u16*)(ws + 52584448);       // 128*512*2      = 131072
  u16*   h1        = (u16*)(ws + 52715520);       // 128*512*2      = 131072
  u16*   hs        = (u16*)(ws + 52846592);       // 4096*512*2     = 4194304  (end 57040896)

  hipMemsetAsync(cbuf, 0, (size_t)BATCH * HIDDEN * 4, stream);
  hipMemsetAsync(h0,   0, (size_t)BATCH * HIDDEN * 2, stream);

  k_feats<<<128, 256, 0, stream>>>(features, W_ft, b_ft, feats_emb);
  k_prep<<<(VOCAB * HIDDEN) / 256, 256, 0, stream>>>(p, W_fc, WcatT, UcatT, bcat, Wfc_bf);
  k_build_x<<<(TSTEPS * BATCH * 2 * EMBED) / 256, 256, 0, stream>>>(emb, captions, feats_emb, X);

  // gates_pre = X @ WcatT^T + bcat   (M=4096, N=2048, K=512)
  k_gemm_bt<<<dim3(2048 / 128, 4096 / 128), 256, 0, stream>>>(
      X, WcatT, bcat, gates_pre, 4096, 2048, 512, 0);

  u16* hb[2] = {h0, h1};
  for (int t = 0; t < TSTEPS; ++t) {
    k_lstm_step<<<16, 256, 0, stream>>>(
        hb[t & 1], UcatT, gates_pre + (size_t)t * BATCH * 4 * HIDDEN, cbuf,
        hb[(t + 1) & 1], hs + (size_t)t * BATCH * HIDDEN);
  }

  // out[b][t][v] = hs @ Wfc^T + b_fc  (M=4096, N=10000, K=512, remapped store)
  k_gemm_bt<<<dim3((VOCAB + 127) / 128, 4096 / 128), 256, 0, stream>>>(
      hs, Wfc_bf, b_fc, out, 4096, VOCAB, 512, 1);
}

// Round 2
// 459.685 us; speedup vs baseline: 1.8312x; 1.8312x over previous
//
#include <hip/hip_runtime.h>
#include <hip/hip_bf16.h>

// Problem constants
#define EMBED    256
#define HIDDEN   512
#define VOCAB    10000
#define FEAT_DIM 1024
#define BATCH    128
#define NREGS    49
#define TSTEPS   32      // CAPLEN-1

typedef unsigned short u16;
using f32x4 = __attribute__((ext_vector_type(4))) float;
using s16x8 = __attribute__((ext_vector_type(8))) short;

__device__ __forceinline__ u16 f2bf(float f) {
  __hip_bfloat16 h = __float2bfloat16(f);
  return *reinterpret_cast<u16*>(&h);
}
__device__ __forceinline__ float sig_(float x) {
  return 1.0f / (1.0f + __expf(-x));
}
__device__ __forceinline__ float tanh_(float x) {
  x = fminf(fmaxf(x, -15.f), 15.f);
  float e = __expf(2.f * x);
  return (e - 1.f) / (e + 1.f);
}

// ---------------------------------------------------------------------------
// Kernel 1: feats_emb[b][e] = (mean_r features[b][r][:]) . W_ft[e][:] + b_ft[e]
// ---------------------------------------------------------------------------
__global__ __launch_bounds__(256)
void k_feats(const float* __restrict__ features, const float* __restrict__ W_ft,
             const float* __restrict__ b_ft, float* __restrict__ feats_emb) {
  __shared__ float mean[FEAT_DIM];
  int b = blockIdx.x, tid = threadIdx.x;
  const float* fb = features + (size_t)b * NREGS * FEAT_DIM;
  for (int d = tid; d < FEAT_DIM; d += 256) {
    float s = 0.f;
    for (int r = 0; r < NREGS; ++r) s += fb[r * FEAT_DIM + d];
    mean[d] = s * (1.0f / 49.0f);
  }
  __syncthreads();
  const float* w = W_ft + (size_t)tid * FEAT_DIM;
  float acc = b_ft[tid];
#pragma unroll 4
  for (int d = 0; d < FEAT_DIM; d += 4) {
    float4 m4 = *(const float4*)&mean[d];
    float4 w4 = *(const float4*)&w[d];
    acc += m4.x * w4.x + m4.y * w4.y + m4.z * w4.z + m4.w * w4.w;
  }
  feats_emb[b * EMBED + tid] = acc;
}

// ---------------------------------------------------------------------------
struct GatePtrs {
  const float* W[4];
  const float* U[4];
  const float* b[4];
};

// Kernel 2a: LDS-tiled transpose+cast of W/U gate matrices.
// in: [512 k][512 j] f32  ->  out row gc = g*512+j : [gc][k] bf16
__global__ __launch_bounds__(256)
void k_transpose_wu(GatePtrs p, u16* __restrict__ WcatT, u16* __restrict__ UcatT) {
  __shared__ float tile[64][65];
  int g = blockIdx.y;
  const float* src = blockIdx.z ? p.U[g] : p.W[g];
  u16* dst = blockIdx.z ? UcatT : WcatT;
  int tj = (blockIdx.x & 7) * 64;    // j tile
  int tk = (blockIdx.x >> 3) * 64;   // k tile
  int tx = threadIdx.x & 63, ty = threadIdx.x >> 6;
#pragma unroll
  for (int i = 0; i < 16; ++i)
    tile[ty + 4 * i][tx] = src[(size_t)(tk + ty + 4 * i) * HIDDEN + tj + tx];
  __syncthreads();
#pragma unroll
  for (int i = 0; i < 16; ++i)
    dst[(size_t)(g * 512 + tj + ty + 4 * i) * 512 + tk + tx] = f2bf(tile[tx][ty + 4 * i]);
}

// Kernel 2b: Wfc f32->bf16 (vectorized) + bcat
__global__ __launch_bounds__(256)
void k_prep2(GatePtrs p, const float* __restrict__ W_fc,
             float* __restrict__ bcat, u16* __restrict__ Wfc_bf) {
  int idx = blockIdx.x * 256 + threadIdx.x;
  if (idx < VOCAB * HIDDEN / 4) {
    float4 v = *(const float4*)(W_fc + (size_t)idx * 4);
    ushort4 o;
    o.x = f2bf(v.x); o.y = f2bf(v.y); o.z = f2bf(v.z); o.w = f2bf(v.w);
    *(ushort4*)(Wfc_bf + (size_t)idx * 4) = o;
  }
  if (idx < 4 * HIDDEN) bcat[idx] = p.b[idx >> 9][idx & 511];
}

// ---------------------------------------------------------------------------
// Kernel 3: build X (bf16): row r = t*128+b, cols [emb[cap[b][t]] | feats_emb[b]]
// ---------------------------------------------------------------------------
__global__ __launch_bounds__(256)
void k_build_x(const float* __restrict__ emb, const int* __restrict__ captions,
               const float* __restrict__ feats_emb, u16* __restrict__ X) {
  int idx = blockIdx.x * 256 + threadIdx.x;
  int r = idx >> 9, col = idx & 511;
  int t = r >> 7, b = r & 127;
  float v;
  if (col < EMBED) {
    int tok = captions[b * 33 + t];
    v = emb[(size_t)tok * EMBED + col];
  } else {
    v = feats_emb[b * EMBED + (col - EMBED)];
  }
  X[idx] = f2bf(v);
}

// ---------------------------------------------------------------------------
// Kernel 4: bf16 GEMM, C[M][N] = A[M][K] @ Bt[N][K]^T + bias[N]
// 128x128 tile, BK=32, 4 waves; XCD-swizzled (bijective, m-fastest per chunk).
// out_mode 0: row-major MxN. out_mode 1: m=t*128+b -> out[b][t][n]
// ---------------------------------------------------------------------------
#define GSTR 40

__global__ __launch_bounds__(256)
void k_gemm_bt(const u16* __restrict__ A, const u16* __restrict__ Bt,
               const float* __restrict__ bias, float* __restrict__ C,
               int M, int N, int K, int out_mode) {
  __shared__ u16 Al[128 * GSTR];
  __shared__ u16 Bl[128 * GSTR];
  int tid = threadIdx.x;
  int lane = tid & 63;
  int w = tid >> 6;
  int wr = w & 1, wc = w >> 1;

  // bijective XCD swizzle (m204): each XCD gets a contiguous chunk of the
  // n-major/m-minor ordering -> Wfc n-slice + full A stay in its private L2.
  int Mtiles = gridDim.y, Ntiles = gridDim.x;
  int nwg = Mtiles * Ntiles;
  int id = blockIdx.y * Ntiles + blockIdx.x;
  int q = nwg >> 3, r = nwg & 7;
  int xcd = id & 7, pos = id >> 3;
  int wg = (xcd < r ? xcd * (q + 1) : r * (q + 1) + (xcd - r) * q) + pos;
  int m0 = (wg % Mtiles) * 128;
  int n0 = (wg / Mtiles) * 128;

  f32x4 acc[4][4];
#pragma unroll
  for (int i = 0; i < 4; ++i)
#pragma unroll
    for (int j = 0; j < 4; ++j) acc[i][j] = (f32x4){0.f, 0.f, 0.f, 0.f};

  int s0 = tid, s1 = tid + 256;
  int ar0 = s0 >> 2, ak0 = (s0 & 3) * 8;
  int ar1 = s1 >> 2, ak1 = (s1 & 3) * 8;

  for (int k0 = 0; k0 < K; k0 += 32) {
    uint4 a0 = *(const uint4*)(A + (size_t)(m0 + ar0) * K + k0 + ak0);
    uint4 a1 = *(const uint4*)(A + (size_t)(m0 + ar1) * K + k0 + ak1);
    uint4 b0, b1;
    int bn0 = n0 + ar0, bn1 = n0 + ar1;
    if (bn0 < N) b0 = *(const uint4*)(Bt + (size_t)bn0 * K + k0 + ak0);
    else { b0.x = b0.y = b0.z = b0.w = 0u; }
    if (bn1 < N) b1 = *(const uint4*)(Bt + (size_t)bn1 * K + k0 + ak1);
    else { b1.x = b1.y = b1.z = b1.w = 0u; }

    __syncthreads();
    *(uint4*)(Al + ar0 * GSTR + ak0) = a0;
    *(uint4*)(Al + ar1 * GSTR + ak1) = a1;
    *(uint4*)(Bl + ar0 * GSTR + ak0) = b0;
    *(uint4*)(Bl + ar1 * GSTR + ak1) = b1;
    __syncthreads();

    const u16* ab = Al + (wr * 64 + (lane & 15)) * GSTR + (lane >> 4) * 8;
    const u16* bb = Bl + (wc * 64 + (lane & 15)) * GSTR + (lane >> 4) * 8;
    s16x8 af[4], bf_[4];
#pragma unroll
    for (int mi = 0; mi < 4; ++mi) af[mi] = *(const s16x8*)(ab + mi * 16 * GSTR);
#pragma unroll
    for (int ni = 0; ni < 4; ++ni) bf_[ni] = *(const s16x8*)(bb + ni * 16 * GSTR);
#pragma unroll
    for (int mi = 0; mi < 4; ++mi)
#pragma unroll
      for (int ni = 0; ni < 4; ++ni)
        acc[mi][ni] = __builtin_amdgcn_mfma_f32_16x16x32_bf16(af[mi], bf_[ni], acc[mi][ni], 0, 0, 0);
  }

  int rbase = (lane >> 4) * 4;
  int colf = lane & 15;
#pragma unroll
  for (int mi = 0; mi < 4; ++mi) {
    int mbase = m0 + wr * 64 + mi * 16 + rbase;
#pragma unroll
    for (int ni = 0; ni < 4; ++ni) {
      int n = n0 + wc * 64 + ni * 16 + colf;
      if (n < N) {
        float bv = bias[n];
#pragma unroll
        for (int reg = 0; reg < 4; ++reg) {
          int mm = mbase + reg;
          float v = acc[mi][ni][reg] + bv;
          if (out_mode == 0) {
            C[(size_t)mm * N + n] = v;
          } else {
            C[(size_t)(mm & 127) * (TSTEPS * VOCAB) + (size_t)(mm >> 7) * VOCAB + n] = v;
          }
        }
      }
    }
  }
}

// ---------------------------------------------------------------------------
// Kernel 5: persistent LSTM — all 32 steps in one launch.
// Grid 64 = 4 m-groups (32 batch rows) x 16 j-blocks (32 j-cols x 4 gates).
// U-slice (128 gate-cols x 512 k) staged in LDS ONCE (step-invariant).
// c-state in registers. h exchanged via hs[] + per-m-group device barrier.
// ---------------------------------------------------------------------------
#define USTR 520   // padded k-stride: 1040 B -> row stride = 4 banks -> 2-way (free)

__global__ __launch_bounds__(256, 1)
void k_lstm_all(const u16* __restrict__ UcatT, const float* __restrict__ gates_pre,
                u16* __restrict__ hs, int* __restrict__ bar) {
  __shared__ u16 Ul[128 * USTR];   // 133,120 B
  int tid = threadIdx.x;
  int lane = tid & 63;
  int w = tid >> 6;
  int wr = w & 1, wj = w >> 1;
  int mg = blockIdx.x >> 4;        // 0..3  (batch rows 32*mg..+31)
  int jb = blockIdx.x & 15;        // 0..15 (j columns 32*jb..+31)
  int b0 = mg * 32;
  int j0 = jb * 32;

  // stage U-slice: rows gc = gi*32 + jj_local, 512 k each
  for (int i = tid; i < 128 * 64; i += 256) {
    int row = i >> 6;
    int kc = (i & 63) * 8;
    int gr = ((row >> 5) << 9) + j0 + (row & 31);
    uint4 v = *(const uint4*)(UcatT + (size_t)gr * 512 + kc);
    *(uint4*)(Ul + row * USTR + kc) = v;
  }
  __syncthreads();

  int jloc = wj * 16 + (lane & 15);   // 0..31
  int jj = j0 + jloc;                 // global j
  int rb = wr * 16 + (lane >> 4) * 4; // row base within m-group (4 rows: rb+reg)
  int arow = b0 + wr * 16 + (lane & 15);
  int akoff = (lane >> 4) * 8;
  const u16* ubase = Ul + (size_t)jloc * USTR + akoff;

  float c[4] = {0.f, 0.f, 0.f, 0.f};
  float gpv[16];

  // prefetch gates_pre for t=0
#pragma unroll
  for (int reg = 0; reg < 4; ++reg)
#pragma unroll
    for (int gi = 0; gi < 4; ++gi)
      gpv[reg * 4 + gi] = gates_pre[((size_t)(b0 + rb + reg)) * 2048 + gi * 512 + jj];

#pragma unroll 1
  for (int t = 0; t < TSTEPS; ++t) {
    f32x4 acc[4];
#pragma unroll
    for (int gi = 0; gi < 4; ++gi) acc[gi] = (f32x4){0.f, 0.f, 0.f, 0.f};

    if (t > 0) {
      // h-tile (A operand) straight from global: 16 vector loads, all in flight
      const u16* abase = hs + ((size_t)(t - 1) * 128 + arow) * 512 + akoff;
      s16x8 af[16];
#pragma unroll
      for (int kk = 0; kk < 16; ++kk)
        af[kk] = *(const s16x8*)(abase + kk * 32);
#pragma unroll
      for (int kk = 0; kk < 16; ++kk) {
#pragma unroll
        for (int gi = 0; gi < 4; ++gi) {
          s16x8 bf_ = *(const s16x8*)(ubase + (size_t)gi * 32 * USTR + kk * 32);
          acc[gi] = __builtin_amdgcn_mfma_f32_16x16x32_bf16(af[kk], bf_, acc[gi], 0, 0, 0);
        }
      }
    }

    // epilogue: full cell in registers
#pragma unroll
    for (int reg = 0; reg < 4; ++reg) {
      float pi = acc[0][reg] + gpv[reg * 4 + 0];
      float pf = acc[1][reg] + gpv[reg * 4 + 1];
      float pg = acc[2][reg] + gpv[reg * 4 + 2];
      float po = acc[3][reg] + gpv[reg * 4 + 3];
      float iv = sig_(pi), fv = sig_(pf), gv = tanh_(pg), ov = sig_(po);
      float cn = fv * c[reg] + iv * gv;
      c[reg] = cn;
      float hn = ov * tanh_(cn);
      hs[((size_t)t * 128 + b0 + rb + reg) * 512 + jj] = f2bf(hn);
    }

    if (t < TSTEPS - 1) {
      // prefetch next step's gates_pre BEFORE the barrier (overlaps spin)
#pragma unroll
      for (int reg = 0; reg < 4; ++reg)
#pragma unroll
        for (int gi = 0; gi < 4; ++gi)
          gpv[reg * 4 + gi] =
              gates_pre[((size_t)(t + 1) * 128 + b0 + rb + reg) * 2048 + gi * 512 + jj];

      // per-m-group device barrier (monotonic counter, 16 blocks)
      __syncthreads();
      if (tid == 0) {
        __threadfence();   // release: publish hs[t]
        __hip_atomic_fetch_add(&bar[mg], 1, __ATOMIC_RELAXED, __HIP_MEMORY_SCOPE_AGENT);
        int target = 16 * (t + 1);
        while (__hip_atomic_load(&bar[mg], __ATOMIC_RELAXED, __HIP_MEMORY_SCOPE_AGENT) < target)
          __builtin_amdgcn_s_sleep(2);
        __threadfence();   // acquire: invalidate stale hs[t] copies
      }
      __syncthreads();
    }
  }
}

// ---------------------------------------------------------------------------
extern "C" void kernel_launch(void* const* d_in, const int* in_sizes, int n_in,
                              void* d_out, int out_size, void* d_ws, size_t ws_size,
                              hipStream_t stream) {
  const float* features = (const float*)d_in[0];
  const int*   captions = (const int*)d_in[1];
  const float* emb      = (const float*)d_in[2];
  const float* W_ft     = (const float*)d_in[3];
  const float* b_ft     = (const float*)d_in[4];
  GatePtrs p;
  p.W[0] = (const float*)d_in[5];  p.U[0] = (const float*)d_in[6];  p.b[0] = (const float*)d_in[7];
  p.W[1] = (const float*)d_in[8];  p.U[1] = (const float*)d_in[9];  p.b[1] = (const float*)d_in[10];
  p.W[2] = (const float*)d_in[11]; p.U[2] = (const float*)d_in[12]; p.b[2] = (const float*)d_in[13];
  p.W[3] = (const float*)d_in[14]; p.U[3] = (const float*)d_in[15]; p.b[3] = (const float*)d_in[16];
  const float* W_fc = (const float*)d_in[17];
  const float* b_fc = (const float*)d_in[18];
  float* out = (float*)d_out;

  // workspace carve-up (bytes)
  char* ws = (char*)d_ws;
  float* feats_emb = (float*)(ws + 0);            // 131072
  u16*   X         = (u16*)(ws + 131072);         // 4 MB
  u16*   WcatT     = (u16*)(ws + 4325376);        // 2 MB
  u16*   UcatT     = (u16*)(ws + 6422528);        // 2 MB
  float* bcat      = (float*)(ws + 8519680);      // 8 KB
  u16*   Wfc_bf    = (u16*)(ws + 8527872);        // 10.24 MB
  float* gates_pre = (float*)(ws + 18767872);     // 33.55 MB
  int*   bar       = (int*)(ws + 52322304);       // 16 B (barrier counters)
  u16*   hs        = (u16*)(ws + 52846592);       // 4 MB

  hipMemsetAsync(bar, 0, 4 * sizeof(int), stream);

  k_feats<<<128, 256, 0, stream>>>(features, W_ft, b_ft, feats_emb);
  k_transpose_wu<<<dim3(64, 4, 2), 256, 0, stream>>>(p, WcatT, UcatT);
  k_prep2<<<(VOCAB * HIDDEN / 4 + 255) / 256, 256, 0, stream>>>(p, W_fc, bcat, Wfc_bf);
  k_build_x<<<(TSTEPS * BATCH * 2 * EMBED) / 256, 256, 0, stream>>>(emb, captions, feats_emb, X);

  // gates_pre = X @ WcatT^T + bcat   (M=4096, N=2048, K=512)
  k_gemm_bt<<<dim3(2048 / 128, 4096 / 128), 256, 0, stream>>>(
      X, WcatT, bcat, gates_pre, 4096, 2048, 512, 0);

  // all 32 LSTM steps in one persistent kernel
  k_lstm_all<<<64, 256, 0, stream>>>(UcatT, gates_pre, hs, bar);

  // out[b][t][v] = hs @ Wfc^T + b_fc  (M=4096, N=10000, K=512, remapped store)
  k_gemm_bt<<<dim3((VOCAB + 127) / 128, 4096 / 128), 256, 0, stream>>>(
      hs, Wfc_bf, b_fc, out, 4096, VOCAB, 512, 1);
}

// Round 3
// 371.032 us; speedup vs baseline: 2.2688x; 1.2389x over previous
//
#include <hip/hip_runtime.h>
#include <hip/hip_bf16.h>

// Problem constants
#define EMBED    256
#define HIDDEN   512
#define VOCAB    10000
#define FEAT_DIM 1024
#define BATCH    128
#define NREGS    49
#define TSTEPS   32      // CAPLEN-1

typedef unsigned short u16;
typedef unsigned long long u64;
using f32x4 = __attribute__((ext_vector_type(4))) float;
using s16x8 = __attribute__((ext_vector_type(8))) short;

__device__ __forceinline__ u16 f2bf(float f) {
  __hip_bfloat16 h = __float2bfloat16(f);
  return *reinterpret_cast<u16*>(&h);
}
__device__ __forceinline__ float sig_(float x) {
  return 1.0f / (1.0f + __expf(-x));
}
__device__ __forceinline__ float tanh_(float x) {
  x = fminf(fmaxf(x, -15.f), 15.f);
  float e = __expf(2.f * x);
  return (e - 1.f) / (e + 1.f);
}

// ---------------------------------------------------------------------------
// Kernel 1: feats_emb[b][e] = (mean_r features[b][r][:]) . W_ft[e][:] + b_ft[e]
// ---------------------------------------------------------------------------
__global__ __launch_bounds__(256)
void k_feats(const float* __restrict__ features, const float* __restrict__ W_ft,
             const float* __restrict__ b_ft, float* __restrict__ feats_emb) {
  __shared__ float mean[FEAT_DIM];
  int b = blockIdx.x, tid = threadIdx.x;
  const float* fb = features + (size_t)b * NREGS * FEAT_DIM;
  for (int d = tid; d < FEAT_DIM; d += 256) {
    float s = 0.f;
    for (int r = 0; r < NREGS; ++r) s += fb[r * FEAT_DIM + d];
    mean[d] = s * (1.0f / 49.0f);
  }
  __syncthreads();
  const float* w = W_ft + (size_t)tid * FEAT_DIM;
  float acc = b_ft[tid];
#pragma unroll 4
  for (int d = 0; d < FEAT_DIM; d += 4) {
    float4 m4 = *(const float4*)&mean[d];
    float4 w4 = *(const float4*)&w[d];
    acc += m4.x * w4.x + m4.y * w4.y + m4.z * w4.z + m4.w * w4.w;
  }
  feats_emb[b * EMBED + tid] = acc;
}

// ---------------------------------------------------------------------------
struct GatePtrs {
  const float* W[4];
  const float* U[4];
  const float* b[4];
};

// Kernel 2a: LDS-tiled transpose+cast of W/U gate matrices.
__global__ __launch_bounds__(256)
void k_transpose_wu(GatePtrs p, u16* __restrict__ WcatT, u16* __restrict__ UcatT) {
  __shared__ float tile[64][65];
  int g = blockIdx.y;
  const float* src = blockIdx.z ? p.U[g] : p.W[g];
  u16* dst = blockIdx.z ? UcatT : WcatT;
  int tj = (blockIdx.x & 7) * 64;
  int tk = (blockIdx.x >> 3) * 64;
  int tx = threadIdx.x & 63, ty = threadIdx.x >> 6;
#pragma unroll
  for (int i = 0; i < 16; ++i)
    tile[ty + 4 * i][tx] = src[(size_t)(tk + ty + 4 * i) * HIDDEN + tj + tx];
  __syncthreads();
#pragma unroll
  for (int i = 0; i < 16; ++i)
    dst[(size_t)(g * 512 + tj + ty + 4 * i) * 512 + tk + tx] = f2bf(tile[tx][ty + 4 * i]);
}

// Kernel 2b: Wfc f32->bf16 (vectorized) + bcat
__global__ __launch_bounds__(256)
void k_prep2(GatePtrs p, const float* __restrict__ W_fc,
             float* __restrict__ bcat, u16* __restrict__ Wfc_bf) {
  int idx = blockIdx.x * 256 + threadIdx.x;
  if (idx < VOCAB * HIDDEN / 4) {
    float4 v = *(const float4*)(W_fc + (size_t)idx * 4);
    ushort4 o;
    o.x = f2bf(v.x); o.y = f2bf(v.y); o.z = f2bf(v.z); o.w = f2bf(v.w);
    *(ushort4*)(Wfc_bf + (size_t)idx * 4) = o;
  }
  if (idx < 4 * HIDDEN) bcat[idx] = p.b[idx >> 9][idx & 511];
}

// ---------------------------------------------------------------------------
// Kernel 3: build X (bf16)
// ---------------------------------------------------------------------------
__global__ __launch_bounds__(256)
void k_build_x(const float* __restrict__ emb, const int* __restrict__ captions,
               const float* __restrict__ feats_emb, u16* __restrict__ X) {
  int idx = blockIdx.x * 256 + threadIdx.x;
  int r = idx >> 9, col = idx & 511;
  int t = r >> 7, b = r & 127;
  float v;
  if (col < EMBED) {
    int tok = captions[b * 33 + t];
    v = emb[(size_t)tok * EMBED + col];
  } else {
    v = feats_emb[b * EMBED + (col - EMBED)];
  }
  X[idx] = f2bf(v);
}

// ---------------------------------------------------------------------------
// Kernel 4: bf16 GEMM, C[M][N] = A[M][K] @ Bt[N][K]^T + bias[N]  (unchanged)
// ---------------------------------------------------------------------------
#define GSTR 40

__global__ __launch_bounds__(256)
void k_gemm_bt(const u16* __restrict__ A, const u16* __restrict__ Bt,
               const float* __restrict__ bias, float* __restrict__ C,
               int M, int N, int K, int out_mode) {
  __shared__ u16 Al[128 * GSTR];
  __shared__ u16 Bl[128 * GSTR];
  int tid = threadIdx.x;
  int lane = tid & 63;
  int w = tid >> 6;
  int wr = w & 1, wc = w >> 1;

  int Mtiles = gridDim.y, Ntiles = gridDim.x;
  int nwg = Mtiles * Ntiles;
  int id = blockIdx.y * Ntiles + blockIdx.x;
  int q = nwg >> 3, r = nwg & 7;
  int xcd = id & 7, pos = id >> 3;
  int wg = (xcd < r ? xcd * (q + 1) : r * (q + 1) + (xcd - r) * q) + pos;
  int m0 = (wg % Mtiles) * 128;
  int n0 = (wg / Mtiles) * 128;

  f32x4 acc[4][4];
#pragma unroll
  for (int i = 0; i < 4; ++i)
#pragma unroll
    for (int j = 0; j < 4; ++j) acc[i][j] = (f32x4){0.f, 0.f, 0.f, 0.f};

  int s0 = tid, s1 = tid + 256;
  int ar0 = s0 >> 2, ak0 = (s0 & 3) * 8;
  int ar1 = s1 >> 2, ak1 = (s1 & 3) * 8;

  for (int k0 = 0; k0 < K; k0 += 32) {
    uint4 a0 = *(const uint4*)(A + (size_t)(m0 + ar0) * K + k0 + ak0);
    uint4 a1 = *(const uint4*)(A + (size_t)(m0 + ar1) * K + k0 + ak1);
    uint4 b0, b1;
    int bn0 = n0 + ar0, bn1 = n0 + ar1;
    if (bn0 < N) b0 = *(const uint4*)(Bt + (size_t)bn0 * K + k0 + ak0);
    else { b0.x = b0.y = b0.z = b0.w = 0u; }
    if (bn1 < N) b1 = *(const uint4*)(Bt + (size_t)bn1 * K + k0 + ak1);
    else { b1.x = b1.y = b1.z = b1.w = 0u; }

    __syncthreads();
    *(uint4*)(Al + ar0 * GSTR + ak0) = a0;
    *(uint4*)(Al + ar1 * GSTR + ak1) = a1;
    *(uint4*)(Bl + ar0 * GSTR + ak0) = b0;
    *(uint4*)(Bl + ar1 * GSTR + ak1) = b1;
    __syncthreads();

    const u16* ab = Al + (wr * 64 + (lane & 15)) * GSTR + (lane >> 4) * 8;
    const u16* bb = Bl + (wc * 64 + (lane & 15)) * GSTR + (lane >> 4) * 8;
    s16x8 af[4], bf_[4];
#pragma unroll
    for (int mi = 0; mi < 4; ++mi) af[mi] = *(const s16x8*)(ab + mi * 16 * GSTR);
#pragma unroll
    for (int ni = 0; ni < 4; ++ni) bf_[ni] = *(const s16x8*)(bb + ni * 16 * GSTR);
#pragma unroll
    for (int mi = 0; mi < 4; ++mi)
#pragma unroll
      for (int ni = 0; ni < 4; ++ni)
        acc[mi][ni] = __builtin_amdgcn_mfma_f32_16x16x32_bf16(af[mi], bf_[ni], acc[mi][ni], 0, 0, 0);
  }

  int rbase = (lane >> 4) * 4;
  int colf = lane & 15;
#pragma unroll
  for (int mi = 0; mi < 4; ++mi) {
    int mbase = m0 + wr * 64 + mi * 16 + rbase;
#pragma unroll
    for (int ni = 0; ni < 4; ++ni) {
      int n = n0 + wc * 64 + ni * 16 + colf;
      if (n < N) {
        float bv = bias[n];
#pragma unroll
        for (int reg = 0; reg < 4; ++reg) {
          int mm = mbase + reg;
          float v = acc[mi][ni][reg] + bv;
          if (out_mode == 0) {
            C[(size_t)mm * N + n] = v;
          } else {
            C[(size_t)(mm & 127) * (TSTEPS * VOCAB) + (size_t)(mm >> 7) * VOCAB + n] = v;
          }
        }
      }
    }
  }
}

// ---------------------------------------------------------------------------
// Kernel 5: persistent LSTM — all 32 steps, ONE launch, NO fences.
// Grid 64 = 4 m-groups x 16 j-blocks. U-slice LDS-resident. c in registers.
// h exchanged via hx[] using relaxed AGENT-scope atomics (sc0 sc1 -> MALL-
// coherent, bypass L1/L2, no buffer_wbl2/inv). __syncthreads() drains vmcnt
// before the flag add, so one relaxed atomic-add publishes the step.
// ---------------------------------------------------------------------------
#define USTR 520

__global__ __launch_bounds__(256, 1)
void k_lstm_all(const u16* __restrict__ UcatT, const float* __restrict__ gates_pre,
                u16* __restrict__ hs, unsigned* __restrict__ hx, int* __restrict__ bar) {
  __shared__ u16 Ul[128 * USTR];   // 133,120 B
  int tid = threadIdx.x;
  int lane = tid & 63;
  int w = tid >> 6;
  int wr = w & 1, wj = w >> 1;
  int mg = blockIdx.x >> 4;        // 0..3  (batch rows 32*mg..+31)
  int jb = blockIdx.x & 15;        // 0..15 (j columns 32*jb..+31)
  int b0 = mg * 32;
  int j0 = jb * 32;

  // stage step-invariant U-slice
  for (int i = tid; i < 128 * 64; i += 256) {
    int row = i >> 6;
    int kc = (i & 63) * 8;
    int gr = ((row >> 5) << 9) + j0 + (row & 31);
    uint4 v = *(const uint4*)(UcatT + (size_t)gr * 512 + kc);
    *(uint4*)(Ul + row * USTR + kc) = v;
  }
  __syncthreads();

  int jloc = wj * 16 + (lane & 15);
  int jj = j0 + jloc;
  int rb = wr * 16 + (lane >> 4) * 4;
  int arow = b0 + wr * 16 + (lane & 15);
  const u16* ubase = Ul + (size_t)jloc * USTR + (lane >> 4) * 8;
  const u64* hx64 = (const u64*)hx;
  int* flag = bar + mg * 64;       // 256B-strided counters, no false sharing

  float c[4] = {0.f, 0.f, 0.f, 0.f};
  float gpv[16];

#pragma unroll
  for (int reg = 0; reg < 4; ++reg)
#pragma unroll
    for (int gi = 0; gi < 4; ++gi)
      gpv[reg * 4 + gi] = gates_pre[((size_t)(b0 + rb + reg)) * 2048 + gi * 512 + jj];

#pragma unroll 1
  for (int t = 0; t < TSTEPS; ++t) {
    f32x4 acc[4];
#pragma unroll
    for (int gi = 0; gi < 4; ++gi) acc[gi] = (f32x4){0.f, 0.f, 0.f, 0.f};

    if (t > 0) {
      // h-tile from MALL: 32 agent-scope u64 loads, all pipelined
      const u64* hrow = hx64 + ((size_t)(t - 1) * 128 + arow) * 128 + (lane >> 4) * 2;
      s16x8 af[16];
#pragma unroll
      for (int kk = 0; kk < 16; ++kk) {
        u64 q0 = __hip_atomic_load(hrow + kk * 8,     __ATOMIC_RELAXED, __HIP_MEMORY_SCOPE_AGENT);
        u64 q1 = __hip_atomic_load(hrow + kk * 8 + 1, __ATOMIC_RELAXED, __HIP_MEMORY_SCOPE_AGENT);
        union { u64 q[2]; s16x8 v; } u;
        u.q[0] = q0; u.q[1] = q1;
        af[kk] = u.v;
      }
#pragma unroll
      for (int kk = 0; kk < 16; ++kk) {
#pragma unroll
        for (int gi = 0; gi < 4; ++gi) {
          s16x8 bf_ = *(const s16x8*)(ubase + (size_t)gi * 32 * USTR + kk * 32);
          acc[gi] = __builtin_amdgcn_mfma_f32_16x16x32_bf16(af[kk], bf_, acc[gi], 0, 0, 0);
        }
      }
    }

    // cell epilogue (all in registers)
#pragma unroll
    for (int reg = 0; reg < 4; ++reg) {
      float pi = acc[0][reg] + gpv[reg * 4 + 0];
      float pf = acc[1][reg] + gpv[reg * 4 + 1];
      float pg = acc[2][reg] + gpv[reg * 4 + 2];
      float po = acc[3][reg] + gpv[reg * 4 + 3];
      float iv = sig_(pi), fv = sig_(pf), gv = tanh_(pg), ov = sig_(po);
      float cn = fv * c[reg] + iv * gv;
      c[reg] = cn;
      float hn = ov * tanh_(cn);
      u16 hb = f2bf(hn);
      hs[((size_t)t * 128 + b0 + rb + reg) * 512 + jj] = hb;   // for final GEMM
      // pack 2 cols/u32, even lanes store to MALL-coherent exchange buffer
      unsigned pv = hb;
      unsigned nv = __shfl_down(pv, 1);
      if ((lane & 1) == 0) {
        unsigned packed = pv | (nv << 16);
        __hip_atomic_store(hx + ((size_t)t * 128 + b0 + rb + reg) * 256 + (jj >> 1),
                           packed, __ATOMIC_RELAXED, __HIP_MEMORY_SCOPE_AGENT);
      }
    }

    if (t < TSTEPS - 1) {
      // prefetch next step's gates_pre (overlaps the wait)
#pragma unroll
      for (int reg = 0; reg < 4; ++reg)
#pragma unroll
        for (int gi = 0; gi < 4; ++gi)
          gpv[reg * 4 + gi] =
              gates_pre[((size_t)(t + 1) * 128 + b0 + rb + reg) * 2048 + gi * 512 + jj];

      // __syncthreads() drains each wave's vmcnt -> hx stores are at MALL.
      __syncthreads();
      if (tid == 0) {
        __hip_atomic_fetch_add(flag, 1, __ATOMIC_RELAXED, __HIP_MEMORY_SCOPE_AGENT);
        int target = 16 * (t + 1);
        while (__hip_atomic_load(flag, __ATOMIC_RELAXED, __HIP_MEMORY_SCOPE_AGENT) < target) {}
      }
      __syncthreads();
    }
  }
}

// ---------------------------------------------------------------------------
extern "C" void kernel_launch(void* const* d_in, const int* in_sizes, int n_in,
                              void* d_out, int out_size, void* d_ws, size_t ws_size,
                              hipStream_t stream) {
  const float* features = (const float*)d_in[0];
  const int*   captions = (const int*)d_in[1];
  const float* emb      = (const float*)d_in[2];
  const float* W_ft     = (const float*)d_in[3];
  const float* b_ft     = (const float*)d_in[4];
  GatePtrs p;
  p.W[0] = (const float*)d_in[5];  p.U[0] = (const float*)d_in[6];  p.b[0] = (const float*)d_in[7];
  p.W[1] = (const float*)d_in[8];  p.U[1] = (const float*)d_in[9];  p.b[1] = (const float*)d_in[10];
  p.W[2] = (const float*)d_in[11]; p.U[2] = (const float*)d_in[12]; p.b[2] = (const float*)d_in[13];
  p.W[3] = (const float*)d_in[14]; p.U[3] = (const float*)d_in[15]; p.b[3] = (const float*)d_in[16];
  const float* W_fc = (const float*)d_in[17];
  const float* b_fc = (const float*)d_in[18];
  float* out = (float*)d_out;

  // workspace carve-up (bytes) — same 57 MB footprint as round 1
  char* ws = (char*)d_ws;
  float*    feats_emb = (float*)(ws + 0);        // 128 KB
  u16*      X         = (u16*)(ws + 131072);     // 4 MB  (dead after gates GEMM)
  unsigned* hx        = (unsigned*)(ws + 131072);// 4 MB  (reuses X region)
  u16*      WcatT     = (u16*)(ws + 4325376);    // 2 MB
  u16*      UcatT     = (u16*)(ws + 6422528);    // 2 MB
  float*    bcat      = (float*)(ws + 8519680);  // 8 KB
  u16*      Wfc_bf    = (u16*)(ws + 8527872);    // 10.24 MB
  float*    gates_pre = (float*)(ws + 18767872); // 33.55 MB
  int*      bar       = (int*)(ws + 52322304);   // 4 x 256B counters
  u16*      hs        = (u16*)(ws + 52846592);   // 4 MB

  hipMemsetAsync(bar, 0, 4 * 64 * sizeof(int), stream);

  k_feats<<<128, 256, 0, stream>>>(features, W_ft, b_ft, feats_emb);
  k_transpose_wu<<<dim3(64, 4, 2), 256, 0, stream>>>(p, WcatT, UcatT);
  k_prep2<<<(VOCAB * HIDDEN / 4 + 255) / 256, 256, 0, stream>>>(p, W_fc, bcat, Wfc_bf);
  k_build_x<<<(TSTEPS * BATCH * 2 * EMBED) / 256, 256, 0, stream>>>(emb, captions, feats_emb, X);

  // gates_pre = X @ WcatT^T + bcat   (M=4096, N=2048, K=512)
  k_gemm_bt<<<dim3(2048 / 128, 4096 / 128), 256, 0, stream>>>(
      X, WcatT, bcat, gates_pre, 4096, 2048, 512, 0);

  // all 32 LSTM steps, fence-free MALL exchange
  k_lstm_all<<<64, 256, 0, stream>>>(UcatT, gates_pre, hs, hx, bar);

  // out[b][t][v] = hs @ Wfc^T + b_fc  (M=4096, N=10000, K=512, remapped store)
  k_gemm_bt<<<dim3((VOCAB + 127) / 128, 4096 / 128), 256, 0, stream>>>(
      hs, Wfc_bf, b_fc, out, 4096, VOCAB, 512, 1);
}